// Round 4
// baseline (4361.739 us; speedup 1.0000x reference)
//
#include <hip/hip_runtime.h>

// Problem constants (fixed by the reference file)
#define NPTS 524288
#define NUMC 128
#define FD   8
#define NBLK 2048          // NPTS / 256
#define ITERS 5
#define PD   16            // k_sums register pipeline depth (float4 blocks in flight)

static_assert(NPTS == NBLK * 256, "grid must tile N exactly");

// ---- workspace layout (bytes) ----
// 0        : centers   float[1024]
// 4096     : flag      int
// 8192     : cnt_inr   int[128]
// 8704     : ctot      int[128]
// 9216     : cbase     int[129]   ([128] = total assigned)
// 10240    : sums      float[1024]
// 16384    : blockhist int[128*2048]    (1 MB)
// 3162112 - 1MB... : idxlist int[NPTS]  (2 MB)  at 16384+1MB
// 3162112  : sorted    float[8*NPTS]    (16 MB) feature-major member-ordered
// total ~19.1 MB

__global__ void k_init(const float* __restrict__ cin, float* __restrict__ cen, int* __restrict__ flag) {
    int t = blockIdx.x * 256 + threadIdx.x;
    if (t < NUMC * FD) cen[t] = cin[t];
    if (t == 0) *flag = 0;
}

__global__ void k_zero(int* __restrict__ cnt_inr) {
    int t = threadIdx.x;
    if (t < NUMC) cnt_inr[t] = 0;
}

// Pass A: per-center count of points with sqrt(dx^2+dy^2) <= 0.32
__global__ void k_count(const float* __restrict__ data, const float* __restrict__ cen,
                        int* __restrict__ cnt_inr, const int* __restrict__ flag) {
    if (*flag) return;
    __shared__ float cx[NUMC], cy[NUMC];
    __shared__ int hist[NUMC];
    int tid = threadIdx.x;
    if (tid < NUMC) { cx[tid] = cen[tid * FD]; cy[tid] = cen[tid * FD + 1]; hist[tid] = 0; }
    __syncthreads();
    size_t j = (size_t)blockIdx.x * 256 + tid;
    float2 p = *(const float2*)(data + j * FD);
    int lane = tid & 63;
    for (int i = 0; i < NUMC; i++) {
        float dx = __fsub_rn(p.x, cx[i]);
        float dy = __fsub_rn(p.y, cy[i]);
        float s  = __fadd_rn(__fmul_rn(dx, dx), __fmul_rn(dy, dy));
        bool in  = (__fsqrt_rn(s) <= 0.32f);
        unsigned long long m = __ballot(in);
        if (lane == 0 && m) atomicAdd(&hist[i], __popcll(m));
    }
    __syncthreads();
    if (tid < NUMC && hist[tid]) atomicAdd(&cnt_inr[tid], hist[tid]);
}

// Pass B: sequential-per-center assignment chain with the freeze quirk.
__global__ void k_assign(const float* __restrict__ data, const float* __restrict__ cen,
                         const int* __restrict__ cnt_inr, int* __restrict__ labels,
                         int* __restrict__ blockhist, const int* __restrict__ flag) {
    if (*flag) return;
    __shared__ float C[NUMC * FD];
    __shared__ int enough[NUMC];
    __shared__ int hist[NUMC];
    int tid = threadIdx.x;
    for (int e = tid; e < NUMC * FD; e += 256) C[e] = cen[e];
    if (tid < NUMC) { enough[tid] = (cnt_inr[tid] > 1); hist[tid] = 0; }
    __syncthreads();
    size_t j = (size_t)blockIdx.x * 256 + tid;
    float4 a = *(const float4*)(data + j * FD);
    float4 b = *(const float4*)(data + j * FD + 4);
    float x[8] = {a.x, a.y, a.z, a.w, b.x, b.y, b.z, b.w};
    int lab = -1;
    float dval = 1000.0f;
    for (int i = 0; i < NUMC; i++) {
        const float* c = &C[i * FD];
        float dx = __fsub_rn(x[0], c[0]);
        float dy = __fsub_rn(x[1], c[1]);
        float s  = __fadd_rn(__fmul_rn(dx, dx), __fmul_rn(dy, dy));
        float sp = __fsqrt_rn(s);
        if (sp <= 0.32f && enough[i]) {
            float t0 = __fadd_rn(__fsub_rn(x[0], c[0]), 1e-6f);
            float ss = __fmul_rn(t0, t0);
            #pragma unroll
            for (int f = 1; f < 8; f++) {
                float tf = __fadd_rn(__fsub_rn(x[f], c[f]), 1e-6f);
                ss = __fadd_rn(ss, __fmul_rn(tf, tf));
            }
            float D = __fsqrt_rn(ss);
            if (D < dval) { dval = D; lab = i; }
            else break;   // reference sets dval=0 -> frozen forever
        }
    }
    labels[j] = lab;
    if (lab >= 0) atomicAdd(&hist[lab], 1);
    __syncthreads();
    if (tid < NUMC) blockhist[tid * NBLK + blockIdx.x] = hist[tid];
}

// Per-cluster exclusive scan over the 2048 block counts
__global__ void k_scan(int* __restrict__ blockhist, int* __restrict__ ctot, const int* __restrict__ flag) {
    if (*flag) return;
    int c = blockIdx.x, tid = threadIdx.x;
    __shared__ int ts[256];
    int base = c * NBLK + tid * 8;
    int v[8], s = 0;
    #pragma unroll
    for (int u = 0; u < 8; u++) { v[u] = blockhist[base + u]; s += v[u]; }
    ts[tid] = s;
    __syncthreads();
    for (int off = 1; off < 256; off <<= 1) {
        int t = (tid >= off) ? ts[tid - off] : 0;
        __syncthreads();
        ts[tid] += t;
        __syncthreads();
    }
    int run = (tid == 0) ? 0 : ts[tid - 1];
    #pragma unroll
    for (int u = 0; u < 8; u++) { int t = v[u]; blockhist[base + u] = run; run += t; }
    if (tid == 255) ctot[c] = run;
}

__global__ void k_base(const int* __restrict__ ctot, int* __restrict__ cbase, const int* __restrict__ flag) {
    if (*flag) return;
    if (threadIdx.x == 0) {
        int r = 0;
        for (int c = 0; c < NUMC; c++) { cbase[c] = r; r += ctot[c]; }
        cbase[NUMC] = r;   // total assigned points
    }
}

// Stable scatter: member indices per cluster, ascending global point index
__global__ void k_scatter(const int* __restrict__ labels, const int* __restrict__ blockhist,
                          const int* __restrict__ cbase, int* __restrict__ idxlist,
                          const int* __restrict__ flag) {
    if (*flag) return;
    __shared__ int sl[256];
    int tid = threadIdx.x;
    int j = blockIdx.x * 256 + tid;
    sl[tid] = labels[j];
    __syncthreads();
    int c = sl[tid];
    if (c >= 0) {
        int rank = 0;
        for (int t = 0; t < tid; t++) rank += (sl[t] == c);
        idxlist[cbase[c] + blockhist[c * NBLK + blockIdx.x] + rank] = j;
    }
}

// Materialize member-ordered data feature-major: sorted[f][pos] = data[idxlist[pos]][f].
// Fully parallel: random float4-pair reads, 8 coalesced write streams.
__global__ void k_reorder(const float* __restrict__ data, const int* __restrict__ idxlist,
                          const int* __restrict__ cbase, float* __restrict__ sorted,
                          const int* __restrict__ flag) {
    if (*flag) return;
    int pos = blockIdx.x * 256 + threadIdx.x;
    if (pos >= cbase[NUMC]) return;
    int rid = idxlist[pos];
    float4 a = *(const float4*)(data + (size_t)rid * FD);
    float4 b = *(const float4*)(data + (size_t)rid * FD + 4);
    sorted[(size_t)0 * NPTS + pos] = a.x;
    sorted[(size_t)1 * NPTS + pos] = a.y;
    sorted[(size_t)2 * NPTS + pos] = a.z;
    sorted[(size_t)3 * NPTS + pos] = a.w;
    sorted[(size_t)4 * NPTS + pos] = b.x;
    sorted[(size_t)5 * NPTS + pos] = b.y;
    sorted[(size_t)6 * NPTS + pos] = b.z;
    sorted[(size_t)7 * NPTS + pos] = b.w;
}

// Exact sequential fp32 segment sums: one wave per cluster, no LDS, no barriers.
// Lane f streams its contiguous feature column with a depth-PD float4 register
// pipeline; add order identical to the reference scatter-add -> bit-exact.
#define ADD4(v) { acc = __fadd_rn(acc, (v).x); acc = __fadd_rn(acc, (v).y); \
                  acc = __fadd_rn(acc, (v).z); acc = __fadd_rn(acc, (v).w); }

__global__ void __launch_bounds__(64) k_sums(const float* __restrict__ sorted,
                       const int* __restrict__ cbase, const int* __restrict__ ctot,
                       float* __restrict__ sums, const int* __restrict__ flag) {
    if (*flag) return;
    int c = blockIdx.x;
    int lane = threadIdx.x;
    int m = ctot[c], base = cbase[c];
    if (lane < FD) {
        const float* col = sorted + (size_t)lane * NPTS + base;
        float acc = 0.0f;
        int A = (4 - (base & 3)) & 3;           // scalar prologue to 16B alignment
        if (A > m) A = m;
        for (int k = 0; k < A; k++) acc = __fadd_rn(acc, col[k]);
        int nv = (m - A) >> 2;                  // aligned float4 blocks
        const float4* vp = (const float4*)(col + A);
        float4 buf[PD];
        #pragma unroll
        for (int d = 0; d < PD; d++) if (d < nv) buf[d] = vp[d];
        int u = 0;
        for (; u + 2 * PD <= nv; u += PD) {
            #pragma unroll
            for (int d = 0; d < PD; d++) {
                float4 v = buf[d];
                ADD4(v);
                buf[d] = vp[u + PD + d];
            }
        }
        #pragma unroll
        for (int d = 0; d < PD; d++) {
            if (u + d < nv) {
                float4 v = buf[d];
                ADD4(v);
                if (u + PD + d < nv) buf[d] = vp[u + PD + d];
            }
        }
        u += PD;
        #pragma unroll
        for (int d = 0; d < PD; d++) {
            if (u + d < nv) { float4 v = buf[d]; ADD4(v); }
        }
        for (int k = A + (nv << 2); k < m; k++) acc = __fadd_rn(acc, col[k]);
        sums[c * FD + lane] = acc;
    }
}

// Center update + convergence flag (1 block)
__global__ void k_update(float* __restrict__ cen, const float* __restrict__ sums,
                         const int* __restrict__ ctot, int* __restrict__ flag) {
    if (*flag) return;
    __shared__ float red[256];
    int tid = threadIdx.x;
    float sq = 0.0f;
    float newv[4];
    int   eidx[4];
    int ne = 0;
    for (int e = tid; e < NUMC * FD; e += 256) {
        int c = e >> 3;
        float oldv = cen[e];
        float cntf = (float)ctot[c];
        float mean = __fdiv_rn(sums[e], fmaxf(cntf, 1.0f));
        float nc = (cntf > 0.0f) ? mean : oldv;
        float d = __fsub_rn(nc, oldv);
        sq = __fadd_rn(sq, __fmul_rn(d, d));
        newv[ne] = nc; eidx[ne] = e; ne++;
    }
    red[tid] = sq;
    __syncthreads();
    for (int off = 128; off > 0; off >>= 1) {
        if (tid < off) red[tid] += red[tid + off];
        __syncthreads();
    }
    for (int u = 0; u < ne; u++) cen[eidx[u]] = newv[u];
    if (tid == 0) {
        float diff = __fsqrt_rn(red[0]);
        if (diff < 1e-4f) *flag = 1;
    }
}

// Finalize: labels staged as int32 in d_out[0..N); convert to float, append centers.
__global__ void k_finish(float* __restrict__ out, const float* __restrict__ cen) {
    size_t i = (size_t)blockIdx.x * 256 + threadIdx.x;
    if (i < NPTS) {
        int v = ((const int*)out)[i];
        out[i] = (float)v;
    } else if (i < NPTS + NUMC * FD) {
        out[i] = cen[i - NPTS];
    }
}

extern "C" void kernel_launch(void* const* d_in, const int* in_sizes, int n_in,
                              void* d_out, int out_size, void* d_ws, size_t ws_size,
                              hipStream_t stream) {
    const float* data = (const float*)d_in[0];
    const float* cen0 = (const float*)d_in[1];
    float* out = (float*)d_out;
    char* ws = (char*)d_ws;

    float* wcen   = (float*)(ws + 0);
    int*   flag   = (int*)(ws + 4096);
    int*   cntinr = (int*)(ws + 8192);
    int*   ctot   = (int*)(ws + 8704);
    int*   cbase  = (int*)(ws + 9216);    // 129 ints
    float* sums   = (float*)(ws + 10240);
    int*   bh     = (int*)(ws + 16384);
    int*   idxl   = (int*)(ws + 16384 + (size_t)NUMC * NBLK * 4);
    float* sorted = (float*)(ws + 16384 + (size_t)NUMC * NBLK * 4 + (size_t)NPTS * 4);
    int*   labels = (int*)d_out;   // staged as int32, converted by k_finish

    k_init<<<4, 256, 0, stream>>>(cen0, wcen, flag);
    for (int it = 0; it < ITERS; ++it) {
        k_zero   <<<1, 256, 0, stream>>>(cntinr);
        k_count  <<<NBLK, 256, 0, stream>>>(data, wcen, cntinr, flag);
        k_assign <<<NBLK, 256, 0, stream>>>(data, wcen, cntinr, labels, bh, flag);
        k_scan   <<<NUMC, 256, 0, stream>>>(bh, ctot, flag);
        k_base   <<<1, 64, 0, stream>>>(ctot, cbase, flag);
        k_scatter<<<NBLK, 256, 0, stream>>>(labels, bh, cbase, idxl, flag);
        k_reorder<<<NBLK, 256, 0, stream>>>(data, idxl, cbase, sorted, flag);
        k_sums   <<<NUMC, 64, 0, stream>>>(sorted, cbase, ctot, sums, flag);
        k_update <<<1, 256, 0, stream>>>(wcen, sums, ctot, flag);
    }
    k_finish<<<(NPTS + NUMC * FD + 255) / 256, 256, 0, stream>>>(out, wcen);
}

// Round 5
// 3103.779 us; speedup vs baseline: 1.4053x; 1.4053x over previous
//
#include <hip/hip_runtime.h>

// Problem constants (fixed by the reference file)
#define NPTS 524288
#define NUMC 128
#define FD   8
#define NBLK 2048          // NPTS / 256
#define ITERS 5
#define PD   48            // k_sums pipeline depth (float4 blocks in flight)
                           // lead = PD*16cyc ~ 770cyc ~ cross-XCD miss latency

static_assert(NPTS == NBLK * 256, "grid must tile N exactly");

__global__ void k_init(const float* __restrict__ cin, float* __restrict__ cen, int* __restrict__ flag) {
    int t = blockIdx.x * 256 + threadIdx.x;
    if (t < NUMC * FD) cen[t] = cin[t];
    if (t == 0) *flag = 0;
}

__global__ void k_zero(int* __restrict__ cnt_inr) {
    int t = threadIdx.x;
    if (t < NUMC) cnt_inr[t] = 0;
}

// Pass A: per-center count of points with sqrt(dx^2+dy^2) <= 0.32
__global__ void k_count(const float* __restrict__ data, const float* __restrict__ cen,
                        int* __restrict__ cnt_inr, const int* __restrict__ flag) {
    if (*flag) return;
    __shared__ float cx[NUMC], cy[NUMC];
    __shared__ int hist[NUMC];
    int tid = threadIdx.x;
    if (tid < NUMC) { cx[tid] = cen[tid * FD]; cy[tid] = cen[tid * FD + 1]; hist[tid] = 0; }
    __syncthreads();
    size_t j = (size_t)blockIdx.x * 256 + tid;
    float2 p = *(const float2*)(data + j * FD);
    int lane = tid & 63;
    for (int i = 0; i < NUMC; i++) {
        float dx = __fsub_rn(p.x, cx[i]);
        float dy = __fsub_rn(p.y, cy[i]);
        float s  = __fadd_rn(__fmul_rn(dx, dx), __fmul_rn(dy, dy));
        bool in  = (__fsqrt_rn(s) <= 0.32f);
        unsigned long long m = __ballot(in);
        if (lane == 0 && m) atomicAdd(&hist[i], __popcll(m));
    }
    __syncthreads();
    if (tid < NUMC && hist[tid]) atomicAdd(&cnt_inr[tid], hist[tid]);
}

// Pass B: sequential-per-center assignment chain with the freeze quirk.
__global__ void k_assign(const float* __restrict__ data, const float* __restrict__ cen,
                         const int* __restrict__ cnt_inr, int* __restrict__ labels,
                         int* __restrict__ blockhist, const int* __restrict__ flag) {
    if (*flag) return;
    __shared__ float C[NUMC * FD];
    __shared__ int enough[NUMC];
    __shared__ int hist[NUMC];
    int tid = threadIdx.x;
    for (int e = tid; e < NUMC * FD; e += 256) C[e] = cen[e];
    if (tid < NUMC) { enough[tid] = (cnt_inr[tid] > 1); hist[tid] = 0; }
    __syncthreads();
    size_t j = (size_t)blockIdx.x * 256 + tid;
    float4 a = *(const float4*)(data + j * FD);
    float4 b = *(const float4*)(data + j * FD + 4);
    float x[8] = {a.x, a.y, a.z, a.w, b.x, b.y, b.z, b.w};
    int lab = -1;
    float dval = 1000.0f;
    for (int i = 0; i < NUMC; i++) {
        const float* c = &C[i * FD];
        float dx = __fsub_rn(x[0], c[0]);
        float dy = __fsub_rn(x[1], c[1]);
        float s  = __fadd_rn(__fmul_rn(dx, dx), __fmul_rn(dy, dy));
        float sp = __fsqrt_rn(s);
        if (sp <= 0.32f && enough[i]) {
            float t0 = __fadd_rn(__fsub_rn(x[0], c[0]), 1e-6f);
            float ss = __fmul_rn(t0, t0);
            #pragma unroll
            for (int f = 1; f < 8; f++) {
                float tf = __fadd_rn(__fsub_rn(x[f], c[f]), 1e-6f);
                ss = __fadd_rn(ss, __fmul_rn(tf, tf));
            }
            float D = __fsqrt_rn(ss);
            if (D < dval) { dval = D; lab = i; }
            else break;   // reference sets dval=0 -> frozen forever
        }
    }
    labels[j] = lab;
    if (lab >= 0) atomicAdd(&hist[lab], 1);
    __syncthreads();
    if (tid < NUMC) blockhist[tid * NBLK + blockIdx.x] = hist[tid];
}

// Per-cluster exclusive scan over the 2048 block counts
__global__ void k_scan(int* __restrict__ blockhist, int* __restrict__ ctot, const int* __restrict__ flag) {
    if (*flag) return;
    int c = blockIdx.x, tid = threadIdx.x;
    __shared__ int ts[256];
    int base = c * NBLK + tid * 8;
    int v[8], s = 0;
    #pragma unroll
    for (int u = 0; u < 8; u++) { v[u] = blockhist[base + u]; s += v[u]; }
    ts[tid] = s;
    __syncthreads();
    for (int off = 1; off < 256; off <<= 1) {
        int t = (tid >= off) ? ts[tid - off] : 0;
        __syncthreads();
        ts[tid] += t;
        __syncthreads();
    }
    int run = (tid == 0) ? 0 : ts[tid - 1];
    #pragma unroll
    for (int u = 0; u < 8; u++) { int t = v[u]; blockhist[base + u] = run; run += t; }
    if (tid == 255) ctot[c] = run;
}

__global__ void k_base(const int* __restrict__ ctot, int* __restrict__ cbase, const int* __restrict__ flag) {
    if (*flag) return;
    if (threadIdx.x == 0) {
        int r = 0;
        for (int c = 0; c < NUMC; c++) { cbase[c] = r; r += ctot[c]; }
        cbase[NUMC] = r;   // total assigned points
    }
}

// Stable scatter: member indices per cluster, ascending global point index
__global__ void k_scatter(const int* __restrict__ labels, const int* __restrict__ blockhist,
                          const int* __restrict__ cbase, int* __restrict__ idxlist,
                          const int* __restrict__ flag) {
    if (*flag) return;
    __shared__ int sl[256];
    int tid = threadIdx.x;
    int j = blockIdx.x * 256 + tid;
    sl[tid] = labels[j];
    __syncthreads();
    int c = sl[tid];
    if (c >= 0) {
        int rank = 0;
        for (int t = 0; t < tid; t++) rank += (sl[t] == c);
        idxlist[cbase[c] + blockhist[c * NBLK + blockIdx.x] + rank] = j;
    }
}

// Materialize member-ordered data feature-major: sorted[f][pos] = data[idxlist[pos]][f].
__global__ void k_reorder(const float* __restrict__ data, const int* __restrict__ idxlist,
                          const int* __restrict__ cbase, float* __restrict__ sorted,
                          const int* __restrict__ flag) {
    if (*flag) return;
    int pos = blockIdx.x * 256 + threadIdx.x;
    if (pos >= cbase[NUMC]) return;
    int rid = idxlist[pos];
    float4 a = *(const float4*)(data + (size_t)rid * FD);
    float4 b = *(const float4*)(data + (size_t)rid * FD + 4);
    sorted[(size_t)0 * NPTS + pos] = a.x;
    sorted[(size_t)1 * NPTS + pos] = a.y;
    sorted[(size_t)2 * NPTS + pos] = a.z;
    sorted[(size_t)3 * NPTS + pos] = a.w;
    sorted[(size_t)4 * NPTS + pos] = b.x;
    sorted[(size_t)5 * NPTS + pos] = b.y;
    sorted[(size_t)6 * NPTS + pos] = b.z;
    sorted[(size_t)7 * NPTS + pos] = b.w;
}

// Exact sequential fp32 segment sums: one wave per cluster, no LDS, no barriers.
// Lane f streams its contiguous feature column with a depth-PD float4 register
// pipeline; add order identical to the reference scatter-add -> bit-exact.
#define ADD4(v) { acc = __fadd_rn(acc, (v).x); acc = __fadd_rn(acc, (v).y); \
                  acc = __fadd_rn(acc, (v).z); acc = __fadd_rn(acc, (v).w); }

__global__ void __launch_bounds__(64) k_sums(const float* __restrict__ sorted,
                       const int* __restrict__ cbase, const int* __restrict__ ctot,
                       float* __restrict__ sums, const int* __restrict__ flag) {
    if (*flag) return;
    int c = blockIdx.x;
    int lane = threadIdx.x;
    int m = ctot[c], base = cbase[c];
    if (lane < FD) {
        const float* col = sorted + (size_t)lane * NPTS + base;
        float acc = 0.0f;
        int A = (4 - (base & 3)) & 3;           // scalar prologue to 16B alignment
        if (A > m) A = m;
        for (int k = 0; k < A; k++) acc = __fadd_rn(acc, col[k]);
        int nv = (m - A) >> 2;                  // aligned float4 blocks
        const float4* vp = (const float4*)(col + A);
        float4 buf[PD];
        #pragma unroll
        for (int d = 0; d < PD; d++) if (d < nv) buf[d] = vp[d];
        int u = 0;
        for (; u + 2 * PD <= nv; u += PD) {
            #pragma unroll
            for (int d = 0; d < PD; d++) {
                float4 v = buf[d];
                ADD4(v);
                buf[d] = vp[u + PD + d];
            }
        }
        #pragma unroll
        for (int d = 0; d < PD; d++) {
            if (u + d < nv) {
                float4 v = buf[d];
                ADD4(v);
                if (u + PD + d < nv) buf[d] = vp[u + PD + d];
            }
        }
        u += PD;
        #pragma unroll
        for (int d = 0; d < PD; d++) {
            if (u + d < nv) { float4 v = buf[d]; ADD4(v); }
        }
        for (int k = A + (nv << 2); k < m; k++) acc = __fadd_rn(acc, col[k]);
        sums[c * FD + lane] = acc;
    }
}

// Center update + convergence flag (1 block)
__global__ void k_update(float* __restrict__ cen, const float* __restrict__ sums,
                         const int* __restrict__ ctot, int* __restrict__ flag) {
    if (*flag) return;
    __shared__ float red[256];
    int tid = threadIdx.x;
    float sq = 0.0f;
    float newv[4];
    int   eidx[4];
    int ne = 0;
    for (int e = tid; e < NUMC * FD; e += 256) {
        int c = e >> 3;
        float oldv = cen[e];
        float cntf = (float)ctot[c];
        float mean = __fdiv_rn(sums[e], fmaxf(cntf, 1.0f));
        float nc = (cntf > 0.0f) ? mean : oldv;
        float d = __fsub_rn(nc, oldv);
        sq = __fadd_rn(sq, __fmul_rn(d, d));
        newv[ne] = nc; eidx[ne] = e; ne++;
    }
    red[tid] = sq;
    __syncthreads();
    for (int off = 128; off > 0; off >>= 1) {
        if (tid < off) red[tid] += red[tid + off];
        __syncthreads();
    }
    for (int u = 0; u < ne; u++) cen[eidx[u]] = newv[u];
    if (tid == 0) {
        float diff = __fsqrt_rn(red[0]);
        if (diff < 1e-4f) *flag = 1;
    }
}

// Finalize: labels staged as int32 in d_out[0..N); convert to float, append centers.
__global__ void k_finish(float* __restrict__ out, const float* __restrict__ cen) {
    size_t i = (size_t)blockIdx.x * 256 + threadIdx.x;
    if (i < NPTS) {
        int v = ((const int*)out)[i];
        out[i] = (float)v;
    } else if (i < NPTS + NUMC * FD) {
        out[i] = cen[i - NPTS];
    }
}

extern "C" void kernel_launch(void* const* d_in, const int* in_sizes, int n_in,
                              void* d_out, int out_size, void* d_ws, size_t ws_size,
                              hipStream_t stream) {
    const float* data = (const float*)d_in[0];
    const float* cen0 = (const float*)d_in[1];
    float* out = (float*)d_out;
    char* ws = (char*)d_ws;

    float* wcen   = (float*)(ws + 0);
    int*   flag   = (int*)(ws + 4096);
    int*   cntinr = (int*)(ws + 8192);
    int*   ctot   = (int*)(ws + 8704);
    int*   cbase  = (int*)(ws + 9216);    // 129 ints
    float* sums   = (float*)(ws + 10240);
    int*   bh     = (int*)(ws + 16384);
    int*   idxl   = (int*)(ws + 16384 + (size_t)NUMC * NBLK * 4);
    float* sorted = (float*)(ws + 16384 + (size_t)NUMC * NBLK * 4 + (size_t)NPTS * 4);
    int*   labels = (int*)d_out;   // staged as int32, converted by k_finish

    k_init<<<4, 256, 0, stream>>>(cen0, wcen, flag);
    for (int it = 0; it < ITERS; ++it) {
        k_zero   <<<1, 256, 0, stream>>>(cntinr);
        k_count  <<<NBLK, 256, 0, stream>>>(data, wcen, cntinr, flag);
        k_assign <<<NBLK, 256, 0, stream>>>(data, wcen, cntinr, labels, bh, flag);
        k_scan   <<<NUMC, 256, 0, stream>>>(bh, ctot, flag);
        k_base   <<<1, 64, 0, stream>>>(ctot, cbase, flag);
        k_scatter<<<NBLK, 256, 0, stream>>>(labels, bh, cbase, idxl, flag);
        k_reorder<<<NBLK, 256, 0, stream>>>(data, idxl, cbase, sorted, flag);
        k_sums   <<<NUMC, 64, 0, stream>>>(sorted, cbase, ctot, sums, flag);
        k_update <<<1, 256, 0, stream>>>(wcen, sums, ctot, flag);
    }
    k_finish<<<(NPTS + NUMC * FD + 255) / 256, 256, 0, stream>>>(out, wcen);
}

// Round 6
// 3020.275 us; speedup vs baseline: 1.4442x; 1.0276x over previous
//
#include <hip/hip_runtime.h>

// Problem constants (fixed by the reference file)
#define NPTS 524288
#define NUMC 128
#define FD   8
#define NBLK 2048          // NPTS / 256
#define ITERS 5

// k_sums LDS ring: RING slots x 8 features x CSZ members (float each)
#define CSZ   256          // members per chunk per feature (64 lanes x 4 floats DMA)
#define FCOL  260          // feature column stride in floats (+4 pad -> lanes 0..7 bank-disjoint)
#define SLOTF (FD * FCOL)  // 2080 floats per slot
#define RING  4            // slots; depth = 3 chunks ahead ~ 3000 cyc >> miss latency

static_assert(NPTS == NBLK * 256, "grid must tile N exactly");

// explicit vmcnt wait as asm: exact instruction + compiler scheduling fence
#define WAITVM(N) asm volatile("s_waitcnt vmcnt(" #N ")" ::: "memory")

__global__ void k_init(const float* __restrict__ cin, float* __restrict__ cen, int* __restrict__ flag) {
    int t = blockIdx.x * 256 + threadIdx.x;
    if (t < NUMC * FD) cen[t] = cin[t];
    if (t == 0) *flag = 0;
}

__global__ void k_zero(int* __restrict__ cnt_inr) {
    int t = threadIdx.x;
    if (t < NUMC) cnt_inr[t] = 0;
}

// Pass A: per-center count of points with sqrt(dx^2+dy^2) <= 0.32
__global__ void k_count(const float* __restrict__ data, const float* __restrict__ cen,
                        int* __restrict__ cnt_inr, const int* __restrict__ flag) {
    if (*flag) return;
    __shared__ float cx[NUMC], cy[NUMC];
    __shared__ int hist[NUMC];
    int tid = threadIdx.x;
    if (tid < NUMC) { cx[tid] = cen[tid * FD]; cy[tid] = cen[tid * FD + 1]; hist[tid] = 0; }
    __syncthreads();
    size_t j = (size_t)blockIdx.x * 256 + tid;
    float2 p = *(const float2*)(data + j * FD);
    int lane = tid & 63;
    for (int i = 0; i < NUMC; i++) {
        float dx = __fsub_rn(p.x, cx[i]);
        float dy = __fsub_rn(p.y, cy[i]);
        float s  = __fadd_rn(__fmul_rn(dx, dx), __fmul_rn(dy, dy));
        bool in  = (__fsqrt_rn(s) <= 0.32f);
        unsigned long long m = __ballot(in);
        if (lane == 0 && m) atomicAdd(&hist[i], __popcll(m));
    }
    __syncthreads();
    if (tid < NUMC && hist[tid]) atomicAdd(&cnt_inr[tid], hist[tid]);
}

// Pass B: sequential-per-center assignment chain with the freeze quirk.
__global__ void k_assign(const float* __restrict__ data, const float* __restrict__ cen,
                         const int* __restrict__ cnt_inr, int* __restrict__ labels,
                         int* __restrict__ blockhist, const int* __restrict__ flag) {
    if (*flag) return;
    __shared__ float C[NUMC * FD];
    __shared__ int enough[NUMC];
    __shared__ int hist[NUMC];
    int tid = threadIdx.x;
    for (int e = tid; e < NUMC * FD; e += 256) C[e] = cen[e];
    if (tid < NUMC) { enough[tid] = (cnt_inr[tid] > 1); hist[tid] = 0; }
    __syncthreads();
    size_t j = (size_t)blockIdx.x * 256 + tid;
    float4 a = *(const float4*)(data + j * FD);
    float4 b = *(const float4*)(data + j * FD + 4);
    float x[8] = {a.x, a.y, a.z, a.w, b.x, b.y, b.z, b.w};
    int lab = -1;
    float dval = 1000.0f;
    for (int i = 0; i < NUMC; i++) {
        const float* c = &C[i * FD];
        float dx = __fsub_rn(x[0], c[0]);
        float dy = __fsub_rn(x[1], c[1]);
        float s  = __fadd_rn(__fmul_rn(dx, dx), __fmul_rn(dy, dy));
        float sp = __fsqrt_rn(s);
        if (sp <= 0.32f && enough[i]) {
            float t0 = __fadd_rn(__fsub_rn(x[0], c[0]), 1e-6f);
            float ss = __fmul_rn(t0, t0);
            #pragma unroll
            for (int f = 1; f < 8; f++) {
                float tf = __fadd_rn(__fsub_rn(x[f], c[f]), 1e-6f);
                ss = __fadd_rn(ss, __fmul_rn(tf, tf));
            }
            float D = __fsqrt_rn(ss);
            if (D < dval) { dval = D; lab = i; }
            else break;   // reference sets dval=0 -> frozen forever
        }
    }
    labels[j] = lab;
    if (lab >= 0) atomicAdd(&hist[lab], 1);
    __syncthreads();
    if (tid < NUMC) blockhist[tid * NBLK + blockIdx.x] = hist[tid];
}

// Per-cluster exclusive scan over the 2048 block counts
__global__ void k_scan(int* __restrict__ blockhist, int* __restrict__ ctot, const int* __restrict__ flag) {
    if (*flag) return;
    int c = blockIdx.x, tid = threadIdx.x;
    __shared__ int ts[256];
    int base = c * NBLK + tid * 8;
    int v[8], s = 0;
    #pragma unroll
    for (int u = 0; u < 8; u++) { v[u] = blockhist[base + u]; s += v[u]; }
    ts[tid] = s;
    __syncthreads();
    for (int off = 1; off < 256; off <<= 1) {
        int t = (tid >= off) ? ts[tid - off] : 0;
        __syncthreads();
        ts[tid] += t;
        __syncthreads();
    }
    int run = (tid == 0) ? 0 : ts[tid - 1];
    #pragma unroll
    for (int u = 0; u < 8; u++) { int t = v[u]; blockhist[base + u] = run; run += t; }
    if (tid == 255) ctot[c] = run;
}

__global__ void k_base(const int* __restrict__ ctot, int* __restrict__ cbase, const int* __restrict__ flag) {
    if (*flag) return;
    if (threadIdx.x == 0) {
        int r = 0;
        for (int c = 0; c < NUMC; c++) { cbase[c] = r; r += ctot[c]; }
        cbase[NUMC] = r;   // total assigned points
    }
}

// Stable scatter: member indices per cluster, ascending global point index
__global__ void k_scatter(const int* __restrict__ labels, const int* __restrict__ blockhist,
                          const int* __restrict__ cbase, int* __restrict__ idxlist,
                          const int* __restrict__ flag) {
    if (*flag) return;
    __shared__ int sl[256];
    int tid = threadIdx.x;
    int j = blockIdx.x * 256 + tid;
    sl[tid] = labels[j];
    __syncthreads();
    int c = sl[tid];
    if (c >= 0) {
        int rank = 0;
        for (int t = 0; t < tid; t++) rank += (sl[t] == c);
        idxlist[cbase[c] + blockhist[c * NBLK + blockIdx.x] + rank] = j;
    }
}

// Materialize member-ordered data feature-major: sorted[f][pos] = data[idxlist[pos]][f].
__global__ void k_reorder(const float* __restrict__ data, const int* __restrict__ idxlist,
                          const int* __restrict__ cbase, float* __restrict__ sorted,
                          const int* __restrict__ flag) {
    if (*flag) return;
    int pos = blockIdx.x * 256 + threadIdx.x;
    if (pos >= cbase[NUMC]) return;
    int rid = idxlist[pos];
    float4 a = *(const float4*)(data + (size_t)rid * FD);
    float4 b = *(const float4*)(data + (size_t)rid * FD + 4);
    sorted[(size_t)0 * NPTS + pos] = a.x;
    sorted[(size_t)1 * NPTS + pos] = a.y;
    sorted[(size_t)2 * NPTS + pos] = a.z;
    sorted[(size_t)3 * NPTS + pos] = a.w;
    sorted[(size_t)4 * NPTS + pos] = b.x;
    sorted[(size_t)5 * NPTS + pos] = b.y;
    sorted[(size_t)6 * NPTS + pos] = b.z;
    sorted[(size_t)7 * NPTS + pos] = b.w;
}

// Stage one 256-member chunk of all 8 feature columns into LDS ring slot via
// async DMA (global_load_lds, 16B/lane): no VGPR cost, depth independent of RF.
__device__ __forceinline__ void stage_chunk(const float* __restrict__ srt, int baseA,
                                            int t, int slot, float* sbuf, int lane) {
    const float* g0 = srt + (size_t)baseA + (size_t)t * CSZ + lane * 4;
    float* l0 = sbuf + slot * SLOTF;
    #pragma unroll
    for (int f = 0; f < FD; f++) {
        __builtin_amdgcn_global_load_lds(
            (const __attribute__((address_space(1))) void*)(g0 + (size_t)f * NPTS),
            (__attribute__((address_space(3))) void*)(l0 + f * FCOL),
            16, 0, 0);
    }
}

#define ADD4(v) { acc = __fadd_rn(acc, (v).x); acc = __fadd_rn(acc, (v).y); \
                  acc = __fadd_rn(acc, (v).z); acc = __fadd_rn(acc, (v).w); }

// Exact sequential fp32 segment sums: one wave per cluster. Async-DMA LDS ring
// (3 chunks = ~3000 cyc lead) hides L3/HBM latency; chain consumes via
// ds_read_b128 with a depth-8 register pipe. Add order identical to the
// reference scatter-add -> bit-exact.
__global__ void __launch_bounds__(64) k_sums(const float* __restrict__ sorted,
                       const int* __restrict__ cbase, const int* __restrict__ ctot,
                       float* __restrict__ sums, const int* __restrict__ flag) {
    if (*flag) return;
    __shared__ float sbuf[RING * SLOTF];
    int c = blockIdx.x;
    int lane = threadIdx.x;
    int m = ctot[c], base = cbase[c];
    float acc = 0.0f;
    const float* col = sorted + (size_t)lane * NPTS + base;   // lane<8 chain column

    int A = (4 - (base & 3)) & 3;          // scalar prologue to 16B alignment
    if (A > m) A = m;
    if (lane < FD)
        for (int k = 0; k < A; k++) acc = __fadd_rn(acc, col[k]);

    int mv  = m - A;
    int nch = mv / CSZ;                    // full 256-member chunks
    int baseA = base + A;

    // prologue: stage first min(RING, nch) chunks
    int pre = nch < RING ? nch : RING;
    for (int t = 0; t < pre; t++) stage_chunk(sorted, baseA, t, t, sbuf, lane);

    for (int t = 0; t < nch; t++) {
        if (t + RING < nch + 1 && t + RING - 1 < nch && t >= 1)
            ;   // (staging for t+RING-1 already issued in prologue when t<1)
        if (t + RING - 1 < nch && t >= 1)
            stage_chunk(sorted, baseA, t + RING - 1, (t + RING - 1) & (RING - 1), sbuf, lane);
        // wait chunk t resident: outstanding newer chunks = min(RING,nch-t)-1
        int K = nch - t; if (K > RING) K = RING;
        switch (K - 1) {
            case 0: WAITVM(0);  break;
            case 1: WAITVM(8);  break;
            case 2: WAITVM(16); break;
            default: WAITVM(24); break;
        }
        if (lane < FD) {
            const float* lcol = sbuf + (t & (RING - 1)) * SLOTF + lane * FCOL;
            float4 q[8];
            #pragma unroll
            for (int d = 0; d < 8; d++) q[d] = *(const float4*)(lcol + d * 4);
            #pragma unroll 8
            for (int b = 0; b < 56; b++) {
                float4 v = q[b & 7];
                ADD4(v);
                q[b & 7] = *(const float4*)(lcol + (b + 8) * 4);
            }
            #pragma unroll
            for (int b = 56; b < 64; b++) { float4 v = q[b & 7]; ADD4(v); }
        }
    }

    // tail: members [A + nch*CSZ, m) straight from global (ascending order)
    if (lane < FD) {
        for (int k = A + nch * CSZ; k < m; k++) acc = __fadd_rn(acc, col[k]);
        sums[c * FD + lane] = acc;
    }
}

// Center update + convergence flag (1 block)
__global__ void k_update(float* __restrict__ cen, const float* __restrict__ sums,
                         const int* __restrict__ ctot, int* __restrict__ flag) {
    if (*flag) return;
    __shared__ float red[256];
    int tid = threadIdx.x;
    float sq = 0.0f;
    float newv[4];
    int   eidx[4];
    int ne = 0;
    for (int e = tid; e < NUMC * FD; e += 256) {
        int c = e >> 3;
        float oldv = cen[e];
        float cntf = (float)ctot[c];
        float mean = __fdiv_rn(sums[e], fmaxf(cntf, 1.0f));
        float nc = (cntf > 0.0f) ? mean : oldv;
        float d = __fsub_rn(nc, oldv);
        sq = __fadd_rn(sq, __fmul_rn(d, d));
        newv[ne] = nc; eidx[ne] = e; ne++;
    }
    red[tid] = sq;
    __syncthreads();
    for (int off = 128; off > 0; off >>= 1) {
        if (tid < off) red[tid] += red[tid + off];
        __syncthreads();
    }
    for (int u = 0; u < ne; u++) cen[eidx[u]] = newv[u];
    if (tid == 0) {
        float diff = __fsqrt_rn(red[0]);
        if (diff < 1e-4f) *flag = 1;
    }
}

// Finalize: labels staged as int32 in d_out[0..N); convert to float, append centers.
__global__ void k_finish(float* __restrict__ out, const float* __restrict__ cen) {
    size_t i = (size_t)blockIdx.x * 256 + threadIdx.x;
    if (i < NPTS) {
        int v = ((const int*)out)[i];
        out[i] = (float)v;
    } else if (i < NPTS + NUMC * FD) {
        out[i] = cen[i - NPTS];
    }
}

extern "C" void kernel_launch(void* const* d_in, const int* in_sizes, int n_in,
                              void* d_out, int out_size, void* d_ws, size_t ws_size,
                              hipStream_t stream) {
    const float* data = (const float*)d_in[0];
    const float* cen0 = (const float*)d_in[1];
    float* out = (float*)d_out;
    char* ws = (char*)d_ws;

    float* wcen   = (float*)(ws + 0);
    int*   flag   = (int*)(ws + 4096);
    int*   cntinr = (int*)(ws + 8192);
    int*   ctot   = (int*)(ws + 8704);
    int*   cbase  = (int*)(ws + 9216);    // 129 ints
    float* sums   = (float*)(ws + 10240);
    int*   bh     = (int*)(ws + 16384);
    int*   idxl   = (int*)(ws + 16384 + (size_t)NUMC * NBLK * 4);
    float* sorted = (float*)(ws + 16384 + (size_t)NUMC * NBLK * 4 + (size_t)NPTS * 4);
    int*   labels = (int*)d_out;   // staged as int32, converted by k_finish

    k_init<<<4, 256, 0, stream>>>(cen0, wcen, flag);
    for (int it = 0; it < ITERS; ++it) {
        k_zero   <<<1, 256, 0, stream>>>(cntinr);
        k_count  <<<NBLK, 256, 0, stream>>>(data, wcen, cntinr, flag);
        k_assign <<<NBLK, 256, 0, stream>>>(data, wcen, cntinr, labels, bh, flag);
        k_scan   <<<NUMC, 256, 0, stream>>>(bh, ctot, flag);
        k_base   <<<1, 64, 0, stream>>>(ctot, cbase, flag);
        k_scatter<<<NBLK, 256, 0, stream>>>(labels, bh, cbase, idxl, flag);
        k_reorder<<<NBLK, 256, 0, stream>>>(data, idxl, cbase, sorted, flag);
        k_sums   <<<NUMC, 64, 0, stream>>>(sorted, cbase, ctot, sums, flag);
        k_update <<<1, 256, 0, stream>>>(wcen, sums, ctot, flag);
    }
    k_finish<<<(NPTS + NUMC * FD + 255) / 256, 256, 0, stream>>>(out, wcen);
}

// Round 7
// 2401.682 us; speedup vs baseline: 1.8161x; 1.2576x over previous
//
#include <hip/hip_runtime.h>

// Problem constants (fixed by the reference file)
#define NPTS 524288
#define NUMC 128
#define FD   8
#define NBLK 2048          // NPTS / 256
#define ITERS 5

// k_sums LDS ring: RING slots x 8 features x CSZ members
#define CSZ   512          // members per chunk per feature
#define FCOL  516          // column stride in floats: 516*4B 16B-aligned; 516%32=4 -> lanes 0..7 bank-disjoint
#define SLOTF (FD * FCOL)  // 4128 floats per slot
#define RING  3            // 49536 B LDS; 2-chunk DMA lead ~4000 cyc >> 900 cyc miss

static_assert(NPTS == NBLK * 256, "grid must tile N exactly");

#define WAITVM(N) asm volatile("s_waitcnt vmcnt(" #N ")" ::: "memory")

__global__ void k_init(const float* __restrict__ cin, float* __restrict__ cen, int* __restrict__ flag) {
    int t = blockIdx.x * 256 + threadIdx.x;
    if (t < NUMC * FD) cen[t] = cin[t];
    if (t == 0) *flag = 0;
}

__global__ void k_zero(int* __restrict__ cnt_inr) {
    int t = threadIdx.x;
    if (t < NUMC) cnt_inr[t] = 0;
}

// Pass A: per-center count of points with sqrt(dx^2+dy^2) <= 0.32
__global__ void k_count(const float* __restrict__ data, const float* __restrict__ cen,
                        int* __restrict__ cnt_inr, const int* __restrict__ flag) {
    if (*flag) return;
    __shared__ float cx[NUMC], cy[NUMC];
    __shared__ int hist[NUMC];
    int tid = threadIdx.x;
    if (tid < NUMC) { cx[tid] = cen[tid * FD]; cy[tid] = cen[tid * FD + 1]; hist[tid] = 0; }
    __syncthreads();
    size_t j = (size_t)blockIdx.x * 256 + tid;
    float2 p = *(const float2*)(data + j * FD);
    int lane = tid & 63;
    for (int i = 0; i < NUMC; i++) {
        float dx = __fsub_rn(p.x, cx[i]);
        float dy = __fsub_rn(p.y, cy[i]);
        float s  = __fadd_rn(__fmul_rn(dx, dx), __fmul_rn(dy, dy));
        bool in  = (__fsqrt_rn(s) <= 0.32f);
        unsigned long long m = __ballot(in);
        if (lane == 0 && m) atomicAdd(&hist[i], __popcll(m));
    }
    __syncthreads();
    if (tid < NUMC && hist[tid]) atomicAdd(&cnt_inr[tid], hist[tid]);
}

// Pass B: sequential-per-center assignment chain with the freeze quirk.
__global__ void k_assign(const float* __restrict__ data, const float* __restrict__ cen,
                         const int* __restrict__ cnt_inr, int* __restrict__ labels,
                         int* __restrict__ blockhist, const int* __restrict__ flag) {
    if (*flag) return;
    __shared__ float C[NUMC * FD];
    __shared__ int enough[NUMC];
    __shared__ int hist[NUMC];
    int tid = threadIdx.x;
    for (int e = tid; e < NUMC * FD; e += 256) C[e] = cen[e];
    if (tid < NUMC) { enough[tid] = (cnt_inr[tid] > 1); hist[tid] = 0; }
    __syncthreads();
    size_t j = (size_t)blockIdx.x * 256 + tid;
    float4 a = *(const float4*)(data + j * FD);
    float4 b = *(const float4*)(data + j * FD + 4);
    float x[8] = {a.x, a.y, a.z, a.w, b.x, b.y, b.z, b.w};
    int lab = -1;
    float dval = 1000.0f;
    for (int i = 0; i < NUMC; i++) {
        const float* c = &C[i * FD];
        float dx = __fsub_rn(x[0], c[0]);
        float dy = __fsub_rn(x[1], c[1]);
        float s  = __fadd_rn(__fmul_rn(dx, dx), __fmul_rn(dy, dy));
        float sp = __fsqrt_rn(s);
        if (sp <= 0.32f && enough[i]) {
            float t0 = __fadd_rn(__fsub_rn(x[0], c[0]), 1e-6f);
            float ss = __fmul_rn(t0, t0);
            #pragma unroll
            for (int f = 1; f < 8; f++) {
                float tf = __fadd_rn(__fsub_rn(x[f], c[f]), 1e-6f);
                ss = __fadd_rn(ss, __fmul_rn(tf, tf));
            }
            float D = __fsqrt_rn(ss);
            if (D < dval) { dval = D; lab = i; }
            else break;   // reference sets dval=0 -> frozen forever
        }
    }
    labels[j] = lab;
    if (lab >= 0) atomicAdd(&hist[lab], 1);
    __syncthreads();
    if (tid < NUMC) blockhist[tid * NBLK + blockIdx.x] = hist[tid];
}

// Per-cluster exclusive scan over the 2048 block counts
__global__ void k_scan(int* __restrict__ blockhist, int* __restrict__ ctot, const int* __restrict__ flag) {
    if (*flag) return;
    int c = blockIdx.x, tid = threadIdx.x;
    __shared__ int ts[256];
    int base = c * NBLK + tid * 8;
    int v[8], s = 0;
    #pragma unroll
    for (int u = 0; u < 8; u++) { v[u] = blockhist[base + u]; s += v[u]; }
    ts[tid] = s;
    __syncthreads();
    for (int off = 1; off < 256; off <<= 1) {
        int t = (tid >= off) ? ts[tid - off] : 0;
        __syncthreads();
        ts[tid] += t;
        __syncthreads();
    }
    int run = (tid == 0) ? 0 : ts[tid - 1];
    #pragma unroll
    for (int u = 0; u < 8; u++) { int t = v[u]; blockhist[base + u] = run; run += t; }
    if (tid == 255) ctot[c] = run;
}

__global__ void k_base(const int* __restrict__ ctot, int* __restrict__ cbase, const int* __restrict__ flag) {
    if (*flag) return;
    if (threadIdx.x == 0) {
        int r = 0;
        for (int c = 0; c < NUMC; c++) { cbase[c] = r; r += ctot[c]; }
        cbase[NUMC] = r;   // total assigned points
    }
}

// Stable scatter: member indices per cluster, ascending global point index
__global__ void k_scatter(const int* __restrict__ labels, const int* __restrict__ blockhist,
                          const int* __restrict__ cbase, int* __restrict__ idxlist,
                          const int* __restrict__ flag) {
    if (*flag) return;
    __shared__ int sl[256];
    int tid = threadIdx.x;
    int j = blockIdx.x * 256 + tid;
    sl[tid] = labels[j];
    __syncthreads();
    int c = sl[tid];
    if (c >= 0) {
        int rank = 0;
        for (int t = 0; t < tid; t++) rank += (sl[t] == c);
        idxlist[cbase[c] + blockhist[c * NBLK + blockIdx.x] + rank] = j;
    }
}

// Materialize member-ordered data feature-major: sorted[f][pos] = data[idxlist[pos]][f].
__global__ void k_reorder(const float* __restrict__ data, const int* __restrict__ idxlist,
                          const int* __restrict__ cbase, float* __restrict__ sorted,
                          const int* __restrict__ flag) {
    if (*flag) return;
    int pos = blockIdx.x * 256 + threadIdx.x;
    if (pos >= cbase[NUMC]) return;
    int rid = idxlist[pos];
    float4 a = *(const float4*)(data + (size_t)rid * FD);
    float4 b = *(const float4*)(data + (size_t)rid * FD + 4);
    sorted[(size_t)0 * NPTS + pos] = a.x;
    sorted[(size_t)1 * NPTS + pos] = a.y;
    sorted[(size_t)2 * NPTS + pos] = a.z;
    sorted[(size_t)3 * NPTS + pos] = a.w;
    sorted[(size_t)4 * NPTS + pos] = b.x;
    sorted[(size_t)5 * NPTS + pos] = b.y;
    sorted[(size_t)6 * NPTS + pos] = b.z;
    sorted[(size_t)7 * NPTS + pos] = b.w;
}

// Stage one 512-member chunk (all 8 features) into an LDS ring slot via async
// DMA: 16 x global_load_lds(16B/lane), no VGPR cost. LDS dest is wave-uniform
// base; HW deposits lane i at base + 16*i -> contiguous 256-float half-columns.
__device__ __forceinline__ void stage_chunk(const float* __restrict__ srt, int baseA,
                                            int t, int slot, float* sbuf, int lane) {
    const float* g0 = srt + (size_t)baseA + (size_t)t * CSZ + lane * 4;
    float* l0 = sbuf + slot * SLOTF;
    #pragma unroll
    for (int f = 0; f < FD; f++) {
        __builtin_amdgcn_global_load_lds(
            (const __attribute__((address_space(1))) void*)(g0 + (size_t)f * NPTS),
            (__attribute__((address_space(3))) void*)(l0 + f * FCOL),
            16, 0, 0);
        __builtin_amdgcn_global_load_lds(
            (const __attribute__((address_space(1))) void*)(g0 + (size_t)f * NPTS + 256),
            (__attribute__((address_space(3))) void*)(l0 + f * FCOL + 256),
            16, 0, 0);
    }
}

#define ADD4(v) { acc = __fadd_rn(acc, (v).x); acc = __fadd_rn(acc, (v).y); \
                  acc = __fadd_rn(acc, (v).z); acc = __fadd_rn(acc, (v).w); }

// Exact sequential fp32 segment sums: one wave per cluster. 2-chunk async DMA
// lead; chain lanes 0..7 consume via 16-deep ds_read_b128 pipe whose issues
// hide in the 4-cyc dependent-add stall slots. Add order identical to the
// reference scatter-add -> bit-exact.
__global__ void __launch_bounds__(64) k_sums(const float* __restrict__ sorted,
                       const int* __restrict__ cbase, const int* __restrict__ ctot,
                       float* __restrict__ sums, const int* __restrict__ flag) {
    if (*flag) return;
    __shared__ float sbuf[RING * SLOTF];
    int c = blockIdx.x;
    int lane = threadIdx.x;
    int m = ctot[c], base = cbase[c];
    float acc = 0.0f;
    const float* col = sorted + (size_t)lane * NPTS + base;   // lane<8 chain column

    int A = (4 - (base & 3)) & 3;          // scalar prologue to 16B alignment
    if (A > m) A = m;
    if (lane < FD)
        for (int k = 0; k < A; k++) acc = __fadd_rn(acc, col[k]);

    int baseA = base + A;
    int nch = (m - A) / CSZ;               // full 512-member chunks

    int pre = nch < RING ? nch : RING;
    for (int t = 0; t < pre; t++) stage_chunk(sorted, baseA, t, t, sbuf, lane);

    int slot = 0;
    for (int t = 0; t < nch; t++) {
        if (t >= 1 && t + 2 < nch)
            stage_chunk(sorted, baseA, t + 2, slot == 0 ? 2 : slot - 1, sbuf, lane);
        int K = nch - 1 - t; if (K > 2) K = 2;   // chunks staged beyond t
        switch (K) {
            case 0: WAITVM(0);  break;
            case 1: WAITVM(16); break;
            default: WAITVM(32); break;
        }
        if (lane < FD) {
            const float* lcol = sbuf + slot * SLOTF + lane * FCOL;
            const float4* lv = (const float4*)lcol;
            float4 q[16];
            #pragma unroll
            for (int d = 0; d < 16; d++) q[d] = lv[d];
            #pragma unroll 16
            for (int b = 0; b < 112; b++) {
                float4 v = q[b & 15];
                ADD4(v);
                q[b & 15] = lv[b + 16];
            }
            #pragma unroll
            for (int b = 112; b < 128; b++) { float4 v = q[b & 15]; ADD4(v); }
        }
        slot = (slot == RING - 1) ? 0 : slot + 1;
    }

    // tail: members [A + nch*CSZ, m) from global, float4 depth-8 pipe (aligned)
    if (lane < FD) {
        int start = A + nch * CSZ;
        int rem = m - start;
        const float* tcol = col + start;
        int tv = rem >> 2;
        const float4* tvp = (const float4*)tcol;
        float4 tb[8];
        #pragma unroll
        for (int d = 0; d < 8; d++) if (d < tv) tb[d] = tvp[d];
        int u = 0;
        for (; u + 16 <= tv; u += 8) {
            #pragma unroll
            for (int d = 0; d < 8; d++) {
                float4 v = tb[d];
                ADD4(v);
                tb[d] = tvp[u + 8 + d];
            }
        }
        #pragma unroll
        for (int d = 0; d < 8; d++) {
            if (u + d < tv) {
                float4 v = tb[d];
                ADD4(v);
                if (u + 8 + d < tv) tb[d] = tvp[u + 8 + d];
            }
        }
        u += 8;
        #pragma unroll
        for (int d = 0; d < 8; d++) {
            if (u + d < tv) { float4 v = tb[d]; ADD4(v); }
        }
        for (int k = tv << 2; k < rem; k++) acc = __fadd_rn(acc, tcol[k]);
        sums[c * FD + lane] = acc;
    }
}

// Center update + convergence flag (1 block)
__global__ void k_update(float* __restrict__ cen, const float* __restrict__ sums,
                         const int* __restrict__ ctot, int* __restrict__ flag) {
    if (*flag) return;
    __shared__ float red[256];
    int tid = threadIdx.x;
    float sq = 0.0f;
    float newv[4];
    int   eidx[4];
    int ne = 0;
    for (int e = tid; e < NUMC * FD; e += 256) {
        int c = e >> 3;
        float oldv = cen[e];
        float cntf = (float)ctot[c];
        float mean = __fdiv_rn(sums[e], fmaxf(cntf, 1.0f));
        float nc = (cntf > 0.0f) ? mean : oldv;
        float d = __fsub_rn(nc, oldv);
        sq = __fadd_rn(sq, __fmul_rn(d, d));
        newv[ne] = nc; eidx[ne] = e; ne++;
    }
    red[tid] = sq;
    __syncthreads();
    for (int off = 128; off > 0; off >>= 1) {
        if (tid < off) red[tid] += red[tid + off];
        __syncthreads();
    }
    for (int u = 0; u < ne; u++) cen[eidx[u]] = newv[u];
    if (tid == 0) {
        float diff = __fsqrt_rn(red[0]);
        if (diff < 1e-4f) *flag = 1;
    }
}

// Finalize: labels staged as int32 in d_out[0..N); convert to float, append centers.
__global__ void k_finish(float* __restrict__ out, const float* __restrict__ cen) {
    size_t i = (size_t)blockIdx.x * 256 + threadIdx.x;
    if (i < NPTS) {
        int v = ((const int*)out)[i];
        out[i] = (float)v;
    } else if (i < NPTS + NUMC * FD) {
        out[i] = cen[i - NPTS];
    }
}

extern "C" void kernel_launch(void* const* d_in, const int* in_sizes, int n_in,
                              void* d_out, int out_size, void* d_ws, size_t ws_size,
                              hipStream_t stream) {
    const float* data = (const float*)d_in[0];
    const float* cen0 = (const float*)d_in[1];
    float* out = (float*)d_out;
    char* ws = (char*)d_ws;

    float* wcen   = (float*)(ws + 0);
    int*   flag   = (int*)(ws + 4096);
    int*   cntinr = (int*)(ws + 8192);
    int*   ctot   = (int*)(ws + 8704);
    int*   cbase  = (int*)(ws + 9216);    // 129 ints
    float* sums   = (float*)(ws + 10240);
    int*   bh     = (int*)(ws + 16384);
    int*   idxl   = (int*)(ws + 16384 + (size_t)NUMC * NBLK * 4);
    float* sorted = (float*)(ws + 16384 + (size_t)NUMC * NBLK * 4 + (size_t)NPTS * 4);
    int*   labels = (int*)d_out;   // staged as int32, converted by k_finish

    k_init<<<4, 256, 0, stream>>>(cen0, wcen, flag);
    for (int it = 0; it < ITERS; ++it) {
        k_zero   <<<1, 256, 0, stream>>>(cntinr);
        k_count  <<<NBLK, 256, 0, stream>>>(data, wcen, cntinr, flag);
        k_assign <<<NBLK, 256, 0, stream>>>(data, wcen, cntinr, labels, bh, flag);
        k_scan   <<<NUMC, 256, 0, stream>>>(bh, ctot, flag);
        k_base   <<<1, 64, 0, stream>>>(ctot, cbase, flag);
        k_scatter<<<NBLK, 256, 0, stream>>>(labels, bh, cbase, idxl, flag);
        k_reorder<<<NBLK, 256, 0, stream>>>(data, idxl, cbase, sorted, flag);
        k_sums   <<<NUMC, 64, 0, stream>>>(sorted, cbase, ctot, sums, flag);
        k_update <<<1, 256, 0, stream>>>(wcen, sums, ctot, flag);
    }
    k_finish<<<(NPTS + NUMC * FD + 255) / 256, 256, 0, stream>>>(out, wcen);
}

// Round 8
// 2315.317 us; speedup vs baseline: 1.8839x; 1.0373x over previous
//
#include <hip/hip_runtime.h>

// Problem constants (fixed by the reference file)
#define NPTS 524288
#define NUMC 128
#define FD   8
#define NBLK 2048          // NPTS / 256
#define ITERS 5

// k_sums LDS ring: RING slots x 8 features x CSZ members
#define CSZ   512          // members per chunk per feature
#define FCOL  516          // column stride in floats: 516*4B 16B-aligned; 516%32=4 -> lanes 0..7 bank-disjoint
#define SLOTF (FD * FCOL)  // 4128 floats per slot
#define RING  3            // 49536 B LDS; 2-chunk DMA lead ~4000 cyc >> 900 cyc miss

static_assert(NPTS == NBLK * 256, "grid must tile N exactly");

#define WAITVM(N) asm volatile("s_waitcnt vmcnt(" #N ")" ::: "memory")

__global__ void k_init(const float* __restrict__ cin, float* __restrict__ cen, int* __restrict__ flag) {
    int t = blockIdx.x * 256 + threadIdx.x;
    if (t < NUMC * FD) cen[t] = cin[t];
    if (t == 0) *flag = 0;
}

__global__ void k_zero(int* __restrict__ cnt_inr) {
    int t = threadIdx.x;
    if (t < NUMC) cnt_inr[t] = 0;
}

// Pass A: per-center count of points with sqrt(dx^2+dy^2) <= 0.32
__global__ void k_count(const float* __restrict__ data, const float* __restrict__ cen,
                        int* __restrict__ cnt_inr, const int* __restrict__ flag) {
    if (*flag) return;
    __shared__ float cx[NUMC], cy[NUMC];
    __shared__ int hist[NUMC];
    int tid = threadIdx.x;
    if (tid < NUMC) { cx[tid] = cen[tid * FD]; cy[tid] = cen[tid * FD + 1]; hist[tid] = 0; }
    __syncthreads();
    size_t j = (size_t)blockIdx.x * 256 + tid;
    float2 p = *(const float2*)(data + j * FD);
    int lane = tid & 63;
    for (int i = 0; i < NUMC; i++) {
        float dx = __fsub_rn(p.x, cx[i]);
        float dy = __fsub_rn(p.y, cy[i]);
        float s  = __fadd_rn(__fmul_rn(dx, dx), __fmul_rn(dy, dy));
        bool in  = (__fsqrt_rn(s) <= 0.32f);
        unsigned long long m = __ballot(in);
        if (lane == 0 && m) atomicAdd(&hist[i], __popcll(m));
    }
    __syncthreads();
    if (tid < NUMC && hist[tid]) atomicAdd(&cnt_inr[tid], hist[tid]);
}

// Pass B: sequential-per-center assignment chain with the freeze quirk.
__global__ void k_assign(const float* __restrict__ data, const float* __restrict__ cen,
                         const int* __restrict__ cnt_inr, int* __restrict__ labels,
                         int* __restrict__ blockhist, const int* __restrict__ flag) {
    if (*flag) return;
    __shared__ float C[NUMC * FD];
    __shared__ int enough[NUMC];
    __shared__ int hist[NUMC];
    int tid = threadIdx.x;
    for (int e = tid; e < NUMC * FD; e += 256) C[e] = cen[e];
    if (tid < NUMC) { enough[tid] = (cnt_inr[tid] > 1); hist[tid] = 0; }
    __syncthreads();
    size_t j = (size_t)blockIdx.x * 256 + tid;
    float4 a = *(const float4*)(data + j * FD);
    float4 b = *(const float4*)(data + j * FD + 4);
    float x[8] = {a.x, a.y, a.z, a.w, b.x, b.y, b.z, b.w};
    int lab = -1;
    float dval = 1000.0f;
    for (int i = 0; i < NUMC; i++) {
        const float* c = &C[i * FD];
        float dx = __fsub_rn(x[0], c[0]);
        float dy = __fsub_rn(x[1], c[1]);
        float s  = __fadd_rn(__fmul_rn(dx, dx), __fmul_rn(dy, dy));
        float sp = __fsqrt_rn(s);
        if (sp <= 0.32f && enough[i]) {
            float t0 = __fadd_rn(__fsub_rn(x[0], c[0]), 1e-6f);
            float ss = __fmul_rn(t0, t0);
            #pragma unroll
            for (int f = 1; f < 8; f++) {
                float tf = __fadd_rn(__fsub_rn(x[f], c[f]), 1e-6f);
                ss = __fadd_rn(ss, __fmul_rn(tf, tf));
            }
            float D = __fsqrt_rn(ss);
            if (D < dval) { dval = D; lab = i; }
            else break;   // reference sets dval=0 -> frozen forever
        }
    }
    labels[j] = lab;
    if (lab >= 0) atomicAdd(&hist[lab], 1);
    __syncthreads();
    if (tid < NUMC) blockhist[tid * NBLK + blockIdx.x] = hist[tid];
}

// Per-cluster exclusive scan over the 2048 block counts
__global__ void k_scan(int* __restrict__ blockhist, int* __restrict__ ctot, const int* __restrict__ flag) {
    if (*flag) return;
    int c = blockIdx.x, tid = threadIdx.x;
    __shared__ int ts[256];
    int base = c * NBLK + tid * 8;
    int v[8], s = 0;
    #pragma unroll
    for (int u = 0; u < 8; u++) { v[u] = blockhist[base + u]; s += v[u]; }
    ts[tid] = s;
    __syncthreads();
    for (int off = 1; off < 256; off <<= 1) {
        int t = (tid >= off) ? ts[tid - off] : 0;
        __syncthreads();
        ts[tid] += t;
        __syncthreads();
    }
    int run = (tid == 0) ? 0 : ts[tid - 1];
    #pragma unroll
    for (int u = 0; u < 8; u++) { int t = v[u]; blockhist[base + u] = run; run += t; }
    if (tid == 255) ctot[c] = run;
}

__global__ void k_base(const int* __restrict__ ctot, int* __restrict__ cbase, const int* __restrict__ flag) {
    if (*flag) return;
    if (threadIdx.x == 0) {
        int r = 0;
        for (int c = 0; c < NUMC; c++) { cbase[c] = r; r += ctot[c]; }
        cbase[NUMC] = r;   // total assigned points
    }
}

// Stable scatter: member indices per cluster, ascending global point index
__global__ void k_scatter(const int* __restrict__ labels, const int* __restrict__ blockhist,
                          const int* __restrict__ cbase, int* __restrict__ idxlist,
                          const int* __restrict__ flag) {
    if (*flag) return;
    __shared__ int sl[256];
    int tid = threadIdx.x;
    int j = blockIdx.x * 256 + tid;
    sl[tid] = labels[j];
    __syncthreads();
    int c = sl[tid];
    if (c >= 0) {
        int rank = 0;
        for (int t = 0; t < tid; t++) rank += (sl[t] == c);
        idxlist[cbase[c] + blockhist[c * NBLK + blockIdx.x] + rank] = j;
    }
}

// Materialize member-ordered data feature-major: sorted[f][pos] = data[idxlist[pos]][f].
__global__ void k_reorder(const float* __restrict__ data, const int* __restrict__ idxlist,
                          const int* __restrict__ cbase, float* __restrict__ sorted,
                          const int* __restrict__ flag) {
    if (*flag) return;
    int pos = blockIdx.x * 256 + threadIdx.x;
    if (pos >= cbase[NUMC]) return;
    int rid = idxlist[pos];
    float4 a = *(const float4*)(data + (size_t)rid * FD);
    float4 b = *(const float4*)(data + (size_t)rid * FD + 4);
    sorted[(size_t)0 * NPTS + pos] = a.x;
    sorted[(size_t)1 * NPTS + pos] = a.y;
    sorted[(size_t)2 * NPTS + pos] = a.z;
    sorted[(size_t)3 * NPTS + pos] = a.w;
    sorted[(size_t)4 * NPTS + pos] = b.x;
    sorted[(size_t)5 * NPTS + pos] = b.y;
    sorted[(size_t)6 * NPTS + pos] = b.z;
    sorted[(size_t)7 * NPTS + pos] = b.w;
}

// Stage one 512-member chunk (all 8 features) into an LDS ring slot via async
// DMA: 16 x global_load_lds(16B/lane), no VGPR cost.
__device__ __forceinline__ void stage_chunk(const float* __restrict__ srt, int baseA,
                                            int t, int slot, float* sbuf, int lane) {
    const float* g0 = srt + (size_t)baseA + (size_t)t * CSZ + lane * 4;
    float* l0 = sbuf + slot * SLOTF;
    #pragma unroll
    for (int f = 0; f < FD; f++) {
        __builtin_amdgcn_global_load_lds(
            (const __attribute__((address_space(1))) void*)(g0 + (size_t)f * NPTS),
            (__attribute__((address_space(3))) void*)(l0 + f * FCOL),
            16, 0, 0);
        __builtin_amdgcn_global_load_lds(
            (const __attribute__((address_space(1))) void*)(g0 + (size_t)f * NPTS + 256),
            (__attribute__((address_space(3))) void*)(l0 + f * FCOL + 256),
            16, 0, 0);
    }
}

#define ADD4(v) { acc = __fadd_rn(acc, (v).x); acc = __fadd_rn(acc, (v).y); \
                  acc = __fadd_rn(acc, (v).z); acc = __fadd_rn(acc, (v).w); }

// Exact sequential fp32 segment sums: one wave per cluster. 2-chunk async DMA
// lead hides global latency; chain lanes 0..7 consume via a 32-deep
// ds_read_b128 pipe (128 cyc lead >= ~120 cyc LDS latency). Add order
// identical to the reference scatter-add -> bit-exact.
__global__ void __launch_bounds__(64) k_sums(const float* __restrict__ sorted,
                       const int* __restrict__ cbase, const int* __restrict__ ctot,
                       float* __restrict__ sums, const int* __restrict__ flag) {
    if (*flag) return;
    __shared__ float sbuf[RING * SLOTF];
    int c = blockIdx.x;
    int lane = threadIdx.x;
    int m = ctot[c], base = cbase[c];
    float acc = 0.0f;
    const float* col = sorted + (size_t)lane * NPTS + base;   // lane<8 chain column

    int A = (4 - (base & 3)) & 3;          // scalar prologue to 16B alignment
    if (A > m) A = m;
    if (lane < FD)
        for (int k = 0; k < A; k++) acc = __fadd_rn(acc, col[k]);

    int baseA = base + A;
    int nch = (m - A) / CSZ;               // full 512-member chunks

    int pre = nch < RING ? nch : RING;
    for (int t = 0; t < pre; t++) stage_chunk(sorted, baseA, t, t, sbuf, lane);

    int slot = 0;
    for (int t = 0; t < nch; t++) {
        if (t >= 1 && t + 2 < nch)
            stage_chunk(sorted, baseA, t + 2, slot == 0 ? 2 : slot - 1, sbuf, lane);
        int K = nch - 1 - t; if (K > 2) K = 2;   // chunks staged beyond t
        switch (K) {
            case 0: WAITVM(0);  break;
            case 1: WAITVM(16); break;
            default: WAITVM(32); break;
        }
        if (lane < FD) {
            const float* lcol = sbuf + slot * SLOTF + lane * FCOL;
            const float4* lv = (const float4*)lcol;
            float4 q[32];
            #pragma unroll
            for (int d = 0; d < 32; d++) q[d] = lv[d];
            #pragma unroll 32
            for (int b = 0; b < 96; b++) {
                float4 v = q[b & 31];
                ADD4(v);
                q[b & 31] = lv[b + 32];
            }
            #pragma unroll
            for (int b = 96; b < 128; b++) { float4 v = q[b & 31]; ADD4(v); }
        }
        slot = (slot == RING - 1) ? 0 : slot + 1;
    }

    // tail: members [A + nch*CSZ, m) from global, float4 depth-16 pipe (aligned)
    if (lane < FD) {
        int start = A + nch * CSZ;
        int rem = m - start;
        const float* tcol = col + start;
        int tv = rem >> 2;
        const float4* tvp = (const float4*)tcol;
        float4 tb[16];
        #pragma unroll
        for (int d = 0; d < 16; d++) if (d < tv) tb[d] = tvp[d];
        int u = 0;
        for (; u + 32 <= tv; u += 16) {
            #pragma unroll
            for (int d = 0; d < 16; d++) {
                float4 v = tb[d];
                ADD4(v);
                tb[d] = tvp[u + 16 + d];
            }
        }
        #pragma unroll
        for (int d = 0; d < 16; d++) {
            if (u + d < tv) {
                float4 v = tb[d];
                ADD4(v);
                if (u + 16 + d < tv) tb[d] = tvp[u + 16 + d];
            }
        }
        u += 16;
        #pragma unroll
        for (int d = 0; d < 16; d++) {
            if (u + d < tv) { float4 v = tb[d]; ADD4(v); }
        }
        for (int k = tv << 2; k < rem; k++) acc = __fadd_rn(acc, tcol[k]);
        sums[c * FD + lane] = acc;
    }
}

// Center update + convergence flag (1 block)
__global__ void k_update(float* __restrict__ cen, const float* __restrict__ sums,
                         const int* __restrict__ ctot, int* __restrict__ flag) {
    if (*flag) return;
    __shared__ float red[256];
    int tid = threadIdx.x;
    float sq = 0.0f;
    float newv[4];
    int   eidx[4];
    int ne = 0;
    for (int e = tid; e < NUMC * FD; e += 256) {
        int c = e >> 3;
        float oldv = cen[e];
        float cntf = (float)ctot[c];
        float mean = __fdiv_rn(sums[e], fmaxf(cntf, 1.0f));
        float nc = (cntf > 0.0f) ? mean : oldv;
        float d = __fsub_rn(nc, oldv);
        sq = __fadd_rn(sq, __fmul_rn(d, d));
        newv[ne] = nc; eidx[ne] = e; ne++;
    }
    red[tid] = sq;
    __syncthreads();
    for (int off = 128; off > 0; off >>= 1) {
        if (tid < off) red[tid] += red[tid + off];
        __syncthreads();
    }
    for (int u = 0; u < ne; u++) cen[eidx[u]] = newv[u];
    if (tid == 0) {
        float diff = __fsqrt_rn(red[0]);
        if (diff < 1e-4f) *flag = 1;
    }
}

// Finalize: labels staged as int32 in d_out[0..N); convert to float, append centers.
__global__ void k_finish(float* __restrict__ out, const float* __restrict__ cen) {
    size_t i = (size_t)blockIdx.x * 256 + threadIdx.x;
    if (i < NPTS) {
        int v = ((const int*)out)[i];
        out[i] = (float)v;
    } else if (i < NPTS + NUMC * FD) {
        out[i] = cen[i - NPTS];
    }
}

extern "C" void kernel_launch(void* const* d_in, const int* in_sizes, int n_in,
                              void* d_out, int out_size, void* d_ws, size_t ws_size,
                              hipStream_t stream) {
    const float* data = (const float*)d_in[0];
    const float* cen0 = (const float*)d_in[1];
    float* out = (float*)d_out;
    char* ws = (char*)d_ws;

    float* wcen   = (float*)(ws + 0);
    int*   flag   = (int*)(ws + 4096);
    int*   cntinr = (int*)(ws + 8192);
    int*   ctot   = (int*)(ws + 8704);
    int*   cbase  = (int*)(ws + 9216);    // 129 ints
    float* sums   = (float*)(ws + 10240);
    int*   bh     = (int*)(ws + 16384);
    int*   idxl   = (int*)(ws + 16384 + (size_t)NUMC * NBLK * 4);
    float* sorted = (float*)(ws + 16384 + (size_t)NUMC * NBLK * 4 + (size_t)NPTS * 4);
    int*   labels = (int*)d_out;   // staged as int32, converted by k_finish

    k_init<<<4, 256, 0, stream>>>(cen0, wcen, flag);
    for (int it = 0; it < ITERS; ++it) {
        k_zero   <<<1, 256, 0, stream>>>(cntinr);
        k_count  <<<NBLK, 256, 0, stream>>>(data, wcen, cntinr, flag);
        k_assign <<<NBLK, 256, 0, stream>>>(data, wcen, cntinr, labels, bh, flag);
        k_scan   <<<NUMC, 256, 0, stream>>>(bh, ctot, flag);
        k_base   <<<1, 64, 0, stream>>>(ctot, cbase, flag);
        k_scatter<<<NBLK, 256, 0, stream>>>(labels, bh, cbase, idxl, flag);
        k_reorder<<<NBLK, 256, 0, stream>>>(data, idxl, cbase, sorted, flag);
        k_sums   <<<NUMC, 64, 0, stream>>>(sorted, cbase, ctot, sums, flag);
        k_update <<<1, 256, 0, stream>>>(wcen, sums, ctot, flag);
    }
    k_finish<<<(NPTS + NUMC * FD + 255) / 256, 256, 0, stream>>>(out, wcen);
}